// Round 1
// baseline (295.790 us; speedup 1.0000x reference)
//
#include <hip/hip_runtime.h>
#include <stdint.h>

typedef unsigned short u16;
typedef __attribute__((ext_vector_type(8))) __bf16 bf16x8;
typedef __attribute__((ext_vector_type(4))) __bf16 bf16x4;
typedef __attribute__((ext_vector_type(4))) float f32x4;

#define NGROUPS 32
#define TOK 2048
#define IN_F 512
#define OUT_F 512
#define NEXP 8
#define BM 128
#define BN 128
#define BK 64
#define NKT (IN_F / BK)  // 8 K-tiles

__device__ __forceinline__ u16 f2bf(float f) {
    unsigned int u = __float_as_uint(f);
    unsigned int r = (u + 0x7fffu + ((u >> 16) & 1u)) >> 16;  // RNE
    return (u16)r;
}

// ---------------- weight mixing ----------------
// mw[g][o][i] bf16 at base of d_ws (exactly 16 MiB — DO NOT exceed: round-2
// overflow past 16 MiB corrupted the harness's pristine inputs).
// 4-way split over group clusters for parallelism (1024 blocks).
__global__ __launch_bounds__(256) void mix_w_kernel(
    const float* __restrict__ coeff, const float* __restrict__ We,
    const float* __restrict__ Wsh, u16* __restrict__ mw)
{
    __shared__ float cs[NGROUPS * NEXP];
    int tid = threadIdx.x;
    cs[tid] = coeff[tid];
    __syncthreads();

    size_t idx = ((size_t)blockIdx.x * 256 + tid) * 4;  // 4 floats/thread
    f32x4 wsh = *(const f32x4*)(Wsh + idx);
    f32x4 we[NEXP];
#pragma unroll
    for (int e = 0; e < NEXP; ++e)
        we[e] = *(const f32x4*)(We + (size_t)e * OUT_F * IN_F + idx);

    int g0 = blockIdx.y * 8;
    for (int g = g0; g < g0 + 8; ++g) {
        f32x4 a = wsh;
#pragma unroll
        for (int e = 0; e < NEXP; ++e) {
            float c = cs[g * NEXP + e];
            a[0] += c * we[e][0];
            a[1] += c * we[e][1];
            a[2] += c * we[e][2];
            a[3] += c * we[e][3];
        }
        unsigned int ow[2];
        ow[0] = (unsigned int)f2bf(a[0]) | ((unsigned int)f2bf(a[1]) << 16);
        ow[1] = (unsigned int)f2bf(a[2]) | ((unsigned int)f2bf(a[3]) << 16);
        *(uint2*)(mw + (size_t)g * OUT_F * IN_F + idx) = *(const uint2*)ow;
    }
}

// ---------------- grouped GEMM ----------------
// out[g*TOK+t][o] = sum_i x[t][i]*mw[g][o][i] + bias(g,o)
// Both LDS tiles bf16 [row][64], XOR-swizzled: 16B chunk p = c ^ (row&7).
// A: fp32 global -> regs -> cvt -> ds_write_b64 (reg prefetch overlaps MFMA).
// B: global_load_lds, source-chunk XOR-permuted (dest stays lane-linear).
//
// R1 restructure: DOUBLE-BUFFERED LDS, ONE barrier per K-step. Previous
// version issued B's global_load_lds and drained it (barrier vmcnt(0))
// inside the same inter-barrier window -> full HBM latency exposed every
// K-step (MfmaUtil 11%, HBM 22%). Now A[k+1] regs + B[k+1] LDS-direct are
// issued BEFORE the MFMA section on tile k; the single barrier at the end
// of the step finds them (mostly) landed. LDS 64 KB -> 2 blocks/CU.
__global__ __launch_bounds__(256) void gemm_kernel(
    const float* __restrict__ x, const u16* __restrict__ mw,
    const float* __restrict__ coeff, const float* __restrict__ be,
    const float* __restrict__ bsh, float* __restrict__ out)
{
    __shared__ __align__(16) u16 As[2][BM * BK];  // 2 x 16 KB swizzled
    __shared__ __align__(16) u16 Bs[2][BN * BK];  // 2 x 16 KB swizzled

    int bid = blockIdx.x;
    // XCD swizzle: bid%8 = XCD (round-robin heuristic). Each XCD owns 4 whole
    // groups; the 4 ntile-siblings of an A-panel are consecutive on one XCD.
    int xcd = bid & 7;
    int i   = bid >> 3;                 // 0..255 within XCD
    int g = xcd * 4 + (i >> 6);
    int t = i & 63;
    int mtile = t >> 2;
    int ntile = t & 3;

    const float* Ag = x + ((size_t)g * TOK + (size_t)mtile * BM) * IN_F;
    const u16*   Bg = mw + (size_t)g * OUT_F * IN_F + (size_t)ntile * BN * IN_F;

    int tid  = threadIdx.x;
    int lane = tid & 63;
    int wave = tid >> 6;
    int wm = wave >> 1, wn = wave & 1;
    int lm = lane & 15, lq = lane >> 4;

    f32x4 acc[4][4];
#pragma unroll
    for (int mi = 0; mi < 4; ++mi)
#pragma unroll
        for (int ni = 0; ni < 4; ++ni)
            acc[mi][ni] = f32x4{0.f, 0.f, 0.f, 0.f};

    // ---- prologue: stage tile 0 into buffer 0 ----
    f32x4 areg[8];
    // B tile 0: async global->LDS; dest linear in tid (HW constraint),
    // source chunk XOR-permuted within the 128B row segment (coalesced).
#pragma unroll
    for (int q = 0; q < 4; ++q) {
        int r = q * 32 + (tid >> 3);
        int c = (tid & 7) ^ (r & 7);
        __builtin_amdgcn_global_load_lds(
            (const __attribute__((address_space(1))) void*)(Bg + (size_t)r * IN_F + c * 8),
            (__attribute__((address_space(3))) void*)(&Bs[0][((size_t)q * 256 + tid) * 8]),
            16, 0, 0);
    }
    // A tile 0: 8 passes, thread j covers 16B fp32 chunk at tile-linear
    // chunk4 L = j*256+tid -> row=L>>4, col4=(L&15)*4. Coalesced.
#pragma unroll
    for (int j = 0; j < 8; ++j) {
        int L = j * 256 + tid;
        areg[j] = *(const f32x4*)(Ag + (size_t)(L >> 4) * IN_F + (L & 15) * 4);
    }
#pragma unroll
    for (int j = 0; j < 8; ++j) {
        int L = j * 256 + tid;
        int r = L >> 4, c4 = L & 15;
        int p = (c4 >> 1) ^ (r & 7);
        bf16x4 bv;
        bv[0] = (__bf16)areg[j][0];
        bv[1] = (__bf16)areg[j][1];
        bv[2] = (__bf16)areg[j][2];
        bv[3] = (__bf16)areg[j][3];
        *(bf16x4*)(&As[0][r * 64 + p * 8 + (c4 & 1) * 4]) = bv;
    }
    __syncthreads();  // tile 0 ready (drains B0 global_load_lds + A0 ds_writes)

    // ---- main loop: one barrier per K-step ----
#pragma unroll
    for (int kk = 0; kk < NKT; ++kk) {
        const int cur = kk & 1;
        const int nxt = cur ^ 1;
        const int k1 = (kk + 1) * BK;
        const bool more = (kk + 1 < NKT);

        if (more) {
            // Issue next A (regs) FIRST, then next B (LDS-direct): the
            // pre-cvt waitcnt then only waits A (vmcnt(4)), and B stays in
            // flight until the end-of-step barrier — latency hidden under
            // the MFMA section + cvt.
#pragma unroll
            for (int j = 0; j < 8; ++j) {
                int L = j * 256 + tid;
                areg[j] = *(const f32x4*)(Ag + (size_t)(L >> 4) * IN_F + k1 + (L & 15) * 4);
            }
#pragma unroll
            for (int q = 0; q < 4; ++q) {
                int r = q * 32 + (tid >> 3);
                int c = (tid & 7) ^ (r & 7);
                __builtin_amdgcn_global_load_lds(
                    (const __attribute__((address_space(1))) void*)(Bg + (size_t)r * IN_F + k1 + c * 8),
                    (__attribute__((address_space(3))) void*)(&Bs[nxt][((size_t)q * 256 + tid) * 8]),
                    16, 0, 0);
            }
        }

        // compute on buffer [cur]
#pragma unroll
        for (int ks = 0; ks < 2; ++ks) {
            bf16x8 af[4], bfv[4];
#pragma unroll
            for (int mi = 0; mi < 4; ++mi) {
                int r = wm * 64 + mi * 16 + lm;
                int p = (ks * 4 + lq) ^ (r & 7);
                af[mi] = *(const bf16x8*)(&As[cur][r * 64 + p * 8]);
            }
#pragma unroll
            for (int ni = 0; ni < 4; ++ni) {
                int r = wn * 64 + ni * 16 + lm;
                int p = (ks * 4 + lq) ^ (r & 7);
                bfv[ni] = *(const bf16x8*)(&Bs[cur][r * 64 + p * 8]);
            }
#pragma unroll
            for (int mi = 0; mi < 4; ++mi)
#pragma unroll
                for (int ni = 0; ni < 4; ++ni)
                    acc[mi][ni] = __builtin_amdgcn_mfma_f32_16x16x32_bf16(
                        af[mi], bfv[ni], acc[mi][ni], 0, 0, 0);
        }

        if (more) {
            // cvt + swizzled ds_write_b64 into the buffer just freed by the
            // MFMA reads above (safe: same-iteration reads target [cur]).
#pragma unroll
            for (int j = 0; j < 8; ++j) {
                int L = j * 256 + tid;
                int r = L >> 4, c4 = L & 15;
                int p = (c4 >> 1) ^ (r & 7);
                bf16x4 bv;
                bv[0] = (__bf16)areg[j][0];
                bv[1] = (__bf16)areg[j][1];
                bv[2] = (__bf16)areg[j][2];
                bv[3] = (__bf16)areg[j][3];
                *(bf16x4*)(&As[nxt][r * 64 + p * 8 + (c4 & 1) * 4]) = bv;
            }
            __syncthreads();  // single barrier: next tile's B + A writes done
        }
        // last iteration: no barrier needed, epilogue touches no LDS
    }

    // epilogue: C/D layout col=lane&15, row=(lane>>4)*4+reg  [m89/m91]
    int c0 = ntile * BN + wn * 64;
    float cg[NEXP];
#pragma unroll
    for (int e = 0; e < NEXP; ++e) cg[e] = coeff[g * NEXP + e];
    float bias[4];
#pragma unroll
    for (int ni = 0; ni < 4; ++ni) {
        int o = c0 + ni * 16 + lm;
        float v = bsh[o];
#pragma unroll
        for (int e = 0; e < NEXP; ++e) v += cg[e] * be[e * OUT_F + o];
        bias[ni] = v;
    }

    size_t rowbase = (size_t)g * TOK + (size_t)mtile * BM + (size_t)wm * 64;
#pragma unroll
    for (int mi = 0; mi < 4; ++mi) {
#pragma unroll
        for (int rr = 0; rr < 4; ++rr) {
            size_t row = rowbase + mi * 16 + lq * 4 + rr;
            float* orow = out + row * OUT_F;
#pragma unroll
            for (int ni = 0; ni < 4; ++ni)
                orow[c0 + ni * 16 + lm] = acc[mi][ni][rr] + bias[ni];
        }
    }
}

extern "C" void kernel_launch(void* const* d_in, const int* in_sizes, int n_in,
                              void* d_out, int out_size, void* d_ws, size_t ws_size,
                              hipStream_t stream) {
    const float* x     = (const float*)d_in[0];  // [65536][512] fp32
    const float* coeff = (const float*)d_in[1];  // [32][8]
    const float* We    = (const float*)d_in[2];  // [8][512][512]
    const float* be    = (const float*)d_in[3];  // [8][512]
    const float* Wsh   = (const float*)d_in[4];  // [512][512]
    const float* bsh   = (const float*)d_in[5];  // [512]
    float* out = (float*)d_out;

    u16* mw = (u16*)d_ws;  // bf16 [32][512][512] = exactly 16 MiB

    mix_w_kernel<<<dim3(OUT_F * IN_F / (256 * 4), 4), 256, 0, stream>>>(coeff, We, Wsh, mw);

    int grid = NGROUPS * (TOK / BM) * (OUT_F / BN);  // 2048
    gemm_kernel<<<grid, 256, 0, stream>>>(x, mw, coeff, be, bsh, out);
}

// Round 3
// 283.165 us; speedup vs baseline: 1.0446x; 1.0446x over previous
//
#include <hip/hip_runtime.h>
#include <stdint.h>

typedef unsigned short u16;
typedef __attribute__((ext_vector_type(8))) __bf16 bf16x8;
typedef __attribute__((ext_vector_type(4))) __bf16 bf16x4;
typedef __attribute__((ext_vector_type(4))) float f32x4;

#define NGROUPS 32
#define TOK 2048
#define IN_F 512
#define OUT_F 512
#define NEXP 8
#define BM 128
#define BN 128
#define BK 64
#define NKT (IN_F / BK)  // 8 K-tiles

__device__ __forceinline__ u16 f2bf(float f) {
    unsigned int u = __float_as_uint(f);
    unsigned int r = (u + 0x7fffu + ((u >> 16) & 1u)) >> 16;  // RNE
    return (u16)r;
}

// ---------------- weight mixing ----------------
// mw[g][o][i] bf16 at base of d_ws (exactly 16 MiB — DO NOT exceed: round-2
// overflow past 16 MiB corrupted the harness's pristine inputs).
__global__ __launch_bounds__(256) void mix_w_kernel(
    const float* __restrict__ coeff, const float* __restrict__ We,
    const float* __restrict__ Wsh, u16* __restrict__ mw)
{
    __shared__ float cs[NGROUPS * NEXP];
    int tid = threadIdx.x;
    cs[tid] = coeff[tid];
    __syncthreads();

    size_t idx = ((size_t)blockIdx.x * 256 + tid) * 4;  // 4 floats/thread
    f32x4 wsh = *(const f32x4*)(Wsh + idx);
    f32x4 we[NEXP];
#pragma unroll
    for (int e = 0; e < NEXP; ++e)
        we[e] = *(const f32x4*)(We + (size_t)e * OUT_F * IN_F + idx);

    int g0 = blockIdx.y * 8;
    for (int g = g0; g < g0 + 8; ++g) {
        f32x4 a = wsh;
#pragma unroll
        for (int e = 0; e < NEXP; ++e) {
            float c = cs[g * NEXP + e];
            a[0] += c * we[e][0];
            a[1] += c * we[e][1];
            a[2] += c * we[e][2];
            a[3] += c * we[e][3];
        }
        unsigned int ow[2];
        ow[0] = (unsigned int)f2bf(a[0]) | ((unsigned int)f2bf(a[1]) << 16);
        ow[1] = (unsigned int)f2bf(a[2]) | ((unsigned int)f2bf(a[3]) << 16);
        *(uint2*)(mw + (size_t)g * OUT_F * IN_F + idx) = *(const uint2*)ow;
    }
}

// ---------------- grouped GEMM ----------------
// out[g*TOK+t][o] = sum_i x[t][i]*mw[g][o][i] + bias(g,o)
// LDS tiles bf16 [row][64], XOR-swizzled: 16B chunk p = c ^ (row&7).
//
// R3 == R2 resubmission (R2 bench died to a container-level infra failure;
// audit found no hang/fault mechanism in the kernel — uniform barriers,
// in-bounds LDS, sound vmcnt bookkeeping).
//
// Schedule (T4 counted-vmcnt + raw barrier):
//  - Bs TRIPLE-buffered: B[k+2] issued in iter k, read in iter k+2
//    -> 2-iteration flight; never vmcnt(0)-drained in steady state.
//  - __syncthreads (which drains vmcnt(0)) replaced by explicit
//    `s_waitcnt vmcnt(4)` (leaves exactly the 4 newest loads = B[k+2]
//    in flight; in-order completion => B[k+1] + A[k+1] complete) +
//    `s_waitcnt lgkmcnt(0)` (ds op visibility) + raw s_barrier.
//  - ALL fragment ds_reads happen FIRST in the iter body, before any
//    next-tile VMEM issue (avoids compiler alias-ordering ds_reads
//    behind in-flight global_load_lds).
//  - s_setprio(1) around the MFMA cluster (T5).
// LDS = 2*16K (A) + 3*16K (B) = 80 KB -> 2 blocks/CU.
__global__ __launch_bounds__(256) void gemm_kernel(
    const float* __restrict__ x, const u16* __restrict__ mw,
    const float* __restrict__ coeff, const float* __restrict__ be,
    const float* __restrict__ bsh, float* __restrict__ out)
{
    __shared__ __align__(16) u16 As[2][BM * BK];  // 2 x 16 KB swizzled
    __shared__ __align__(16) u16 Bs[3][BN * BK];  // 3 x 16 KB swizzled

    int bid = blockIdx.x;
    // XCD swizzle: bid%8 = XCD. Each XCD owns 4 whole groups; the 4
    // ntile-siblings of an A-panel are consecutive on one XCD.
    int xcd = bid & 7;
    int i   = bid >> 3;                 // 0..255 within XCD
    int g = xcd * 4 + (i >> 6);
    int t = i & 63;
    int mtile = t >> 2;
    int ntile = t & 3;

    const float* Ag = x + ((size_t)g * TOK + (size_t)mtile * BM) * IN_F;
    const u16*   Bg = mw + (size_t)g * OUT_F * IN_F + (size_t)ntile * BN * IN_F;

    int tid  = threadIdx.x;
    int lane = tid & 63;
    int wave = tid >> 6;
    int wm = wave >> 1, wn = wave & 1;
    int lm = lane & 15, lq = lane >> 4;

    f32x4 acc[4][4];
#pragma unroll
    for (int mi = 0; mi < 4; ++mi)
#pragma unroll
        for (int ni = 0; ni < 4; ++ni)
            acc[mi][ni] = f32x4{0.f, 0.f, 0.f, 0.f};

    // ---- prologue ----
    // Issue order matters for vmcnt bookkeeping: A[0] (8 loads) first,
    // then B[0] (4), then B[1] (4).
    f32x4 areg[8];
#pragma unroll
    for (int j = 0; j < 8; ++j) {
        int L = j * 256 + tid;
        areg[j] = *(const f32x4*)(Ag + (size_t)(L >> 4) * IN_F + (L & 15) * 4);
    }
#pragma unroll
    for (int kb = 0; kb < 2; ++kb) {  // B[0] -> Bs[0], B[1] -> Bs[1]
#pragma unroll
        for (int q = 0; q < 4; ++q) {
            int r = q * 32 + (tid >> 3);
            int c = (tid & 7) ^ (r & 7);
            __builtin_amdgcn_global_load_lds(
                (const __attribute__((address_space(1))) void*)(Bg + (size_t)r * IN_F + kb * BK + c * 8),
                (__attribute__((address_space(3))) void*)(&Bs[kb][((size_t)q * 256 + tid) * 8]),
                16, 0, 0);
        }
    }
    // cvt A[0] (compiler auto-waits the 8 A loads; B stays in flight)
#pragma unroll
    for (int j = 0; j < 8; ++j) {
        int L = j * 256 + tid;
        int r = L >> 4, c4 = L & 15;
        int p = (c4 >> 1) ^ (r & 7);
        bf16x4 bv;
        bv[0] = (__bf16)areg[j][0];
        bv[1] = (__bf16)areg[j][1];
        bv[2] = (__bf16)areg[j][2];
        bv[3] = (__bf16)areg[j][3];
        *(bf16x4*)(&As[0][r * 64 + p * 8 + (c4 & 1) * 4]) = bv;
    }
    // B[0] complete (leave B[1] in flight), LDS writes visible, barrier.
    asm volatile("s_waitcnt vmcnt(4)" ::: "memory");
    __builtin_amdgcn_sched_barrier(0);
    asm volatile("s_waitcnt lgkmcnt(0)" ::: "memory");
    __builtin_amdgcn_sched_barrier(0);
    __builtin_amdgcn_s_barrier();

    // ---- main loop: one raw barrier per K-tile, counted vmcnt ----
#pragma unroll
    for (int kk = 0; kk < NKT; ++kk) {
        const int cur  = kk & 1;        // A buffer
        const int bcur = kk % 3;        // B buffer
        const bool moreA = (kk + 1 < NKT);
        const bool moreB = (kk + 2 < NKT);

        // (1) ALL fragment ds_reads for this K-tile FIRST.
        bf16x8 af[2][4], bfv[2][4];
#pragma unroll
        for (int ks = 0; ks < 2; ++ks) {
#pragma unroll
            for (int mi = 0; mi < 4; ++mi) {
                int r = wm * 64 + mi * 16 + lm;
                int p = (ks * 4 + lq) ^ (r & 7);
                af[ks][mi] = *(const bf16x8*)(&As[cur][r * 64 + p * 8]);
            }
#pragma unroll
            for (int ni = 0; ni < 4; ++ni) {
                int r = wn * 64 + ni * 16 + lm;
                int p = (ks * 4 + lq) ^ (r & 7);
                bfv[ks][ni] = *(const bf16x8*)(&Bs[bcur][r * 64 + p * 8]);
            }
        }

        // (2) issue next A (8 reg loads) — consumed by cvt later this iter.
        if (moreA) {
            int k1 = (kk + 1) * BK;
#pragma unroll
            for (int j = 0; j < 8; ++j) {
                int L = j * 256 + tid;
                areg[j] = *(const f32x4*)(Ag + (size_t)(L >> 4) * IN_F + k1 + (L & 15) * 4);
            }
        }
        // (3) issue B[kk+2] -> Bs[(kk+2)%3] (read in iter kk+2; 2-iter flight).
        if (moreB) {
            int k2 = (kk + 2) * BK;
            const int bnxt2 = (kk + 2) % 3;
#pragma unroll
            for (int q = 0; q < 4; ++q) {
                int r = q * 32 + (tid >> 3);
                int c = (tid & 7) ^ (r & 7);
                __builtin_amdgcn_global_load_lds(
                    (const __attribute__((address_space(1))) void*)(Bg + (size_t)r * IN_F + k2 + c * 8),
                    (__attribute__((address_space(3))) void*)(&Bs[bnxt2][((size_t)q * 256 + tid) * 8]),
                    16, 0, 0);
            }
        }

        // (4) MFMA cluster.
        __builtin_amdgcn_s_setprio(1);
#pragma unroll
        for (int ks = 0; ks < 2; ++ks)
#pragma unroll
            for (int mi = 0; mi < 4; ++mi)
#pragma unroll
                for (int ni = 0; ni < 4; ++ni)
                    acc[mi][ni] = __builtin_amdgcn_mfma_f32_16x16x32_bf16(
                        af[ks][mi], bfv[ks][ni], acc[mi][ni], 0, 0, 0);
        __builtin_amdgcn_s_setprio(0);

        // (5) cvt + ds_write A[kk+1] into As[nxt]. Compiler auto-inserts the
        // counted vmcnt for areg (in-order: also completes B[kk+1]).
        if (moreA) {
#pragma unroll
            for (int j = 0; j < 8; ++j) {
                int L = j * 256 + tid;
                int r = L >> 4, c4 = L & 15;
                int p = (c4 >> 1) ^ (r & 7);
                bf16x4 bv;
                bv[0] = (__bf16)areg[j][0];
                bv[1] = (__bf16)areg[j][1];
                bv[2] = (__bf16)areg[j][2];
                bv[3] = (__bf16)areg[j][3];
                *(bf16x4*)(&As[cur ^ 1][r * 64 + p * 8 + (c4 & 1) * 4]) = bv;
            }

            // (6) end-of-iter: guarantee B[kk+1] landed (everything older
            // than the 4 newest = B[kk+2] is complete), ds ops visible,
            // barrier. B[kk+2] stays in flight ACROSS the barrier.
            if (moreB) {
                asm volatile("s_waitcnt vmcnt(4)" ::: "memory");
            } else {
                asm volatile("s_waitcnt vmcnt(0)" ::: "memory");
            }
            __builtin_amdgcn_sched_barrier(0);
            asm volatile("s_waitcnt lgkmcnt(0)" ::: "memory");
            __builtin_amdgcn_sched_barrier(0);
            __builtin_amdgcn_s_barrier();
        }
    }

    // epilogue: C/D layout col=lane&15, row=(lane>>4)*4+reg  [m89/m91]
    int c0 = ntile * BN + wn * 64;
    float cg[NEXP];
#pragma unroll
    for (int e = 0; e < NEXP; ++e) cg[e] = coeff[g * NEXP + e];
    float bias[4];
#pragma unroll
    for (int ni = 0; ni < 4; ++ni) {
        int o = c0 + ni * 16 + lm;
        float v = bsh[o];
#pragma unroll
        for (int e = 0; e < NEXP; ++e) v += cg[e] * be[e * OUT_F + o];
        bias[ni] = v;
    }

    size_t rowbase = (size_t)g * TOK + (size_t)mtile * BM + (size_t)wm * 64;
#pragma unroll
    for (int mi = 0; mi < 4; ++mi) {
#pragma unroll
        for (int rr = 0; rr < 4; ++rr) {
            size_t row = rowbase + mi * 16 + lq * 4 + rr;
            float* orow = out + row * OUT_F;
#pragma unroll
            for (int ni = 0; ni < 4; ++ni)
                orow[c0 + ni * 16 + lm] = acc[mi][ni][rr] + bias[ni];
        }
    }
}

extern "C" void kernel_launch(void* const* d_in, const int* in_sizes, int n_in,
                              void* d_out, int out_size, void* d_ws, size_t ws_size,
                              hipStream_t stream) {
    const float* x     = (const float*)d_in[0];  // [65536][512] fp32
    const float* coeff = (const float*)d_in[1];  // [32][8]
    const float* We    = (const float*)d_in[2];  // [8][512][512]
    const float* be    = (const float*)d_in[3];  // [8][512]
    const float* Wsh   = (const float*)d_in[4];  // [512][512]
    const float* bsh   = (const float*)d_in[5];  // [512]
    float* out = (float*)d_out;

    u16* mw = (u16*)d_ws;  // bf16 [32][512][512] = exactly 16 MiB

    mix_w_kernel<<<dim3(OUT_F * IN_F / (256 * 4), 4), 256, 0, stream>>>(coeff, We, Wsh, mw);

    int grid = NGROUPS * (TOK / BM) * (OUT_F / BN);  // 2048
    gemm_kernel<<<grid, 256, 0, stream>>>(x, mw, coeff, be, bsh, out);
}

// Round 4
// 274.097 us; speedup vs baseline: 1.0791x; 1.0331x over previous
//
#include <hip/hip_runtime.h>
#include <stdint.h>

typedef unsigned short u16;
typedef __attribute__((ext_vector_type(8))) __bf16 bf16x8;
typedef __attribute__((ext_vector_type(4))) __bf16 bf16x4;
typedef __attribute__((ext_vector_type(4))) float f32x4;

#define NGROUPS 32
#define TOK 2048
#define IN_F 512
#define OUT_F 512
#define NEXP 8
#define BM 256
#define BN 256
#define BK 64
#define NKT (IN_F / BK)  // 8 K-tiles

__device__ __forceinline__ u16 f2bf(float f) {
    unsigned int u = __float_as_uint(f);
    unsigned int r = (u + 0x7fffu + ((u >> 16) & 1u)) >> 16;  // RNE
    return (u16)r;
}

// ---------------- weight mixing ----------------
// mw[g][o][i] bf16 at base of d_ws (exactly 16 MiB — DO NOT exceed: round-2
// overflow past 16 MiB corrupted the harness's pristine inputs).
__global__ __launch_bounds__(256) void mix_w_kernel(
    const float* __restrict__ coeff, const float* __restrict__ We,
    const float* __restrict__ Wsh, u16* __restrict__ mw)
{
    __shared__ float cs[NGROUPS * NEXP];
    int tid = threadIdx.x;
    cs[tid] = coeff[tid];
    __syncthreads();

    size_t idx = ((size_t)blockIdx.x * 256 + tid) * 4;  // 4 floats/thread
    f32x4 wsh = *(const f32x4*)(Wsh + idx);
    f32x4 we[NEXP];
#pragma unroll
    for (int e = 0; e < NEXP; ++e)
        we[e] = *(const f32x4*)(We + (size_t)e * OUT_F * IN_F + idx);

    int g0 = blockIdx.y * 8;
    for (int g = g0; g < g0 + 8; ++g) {
        f32x4 a = wsh;
#pragma unroll
        for (int e = 0; e < NEXP; ++e) {
            float c = cs[g * NEXP + e];
            a[0] += c * we[e][0];
            a[1] += c * we[e][1];
            a[2] += c * we[e][2];
            a[3] += c * we[e][3];
        }
        unsigned int ow[2];
        ow[0] = (unsigned int)f2bf(a[0]) | ((unsigned int)f2bf(a[1]) << 16);
        ow[1] = (unsigned int)f2bf(a[2]) | ((unsigned int)f2bf(a[3]) << 16);
        *(uint2*)(mw + (size_t)g * OUT_F * IN_F + idx) = *(const uint2*)ow;
    }
}

// ---------------- grouped GEMM ----------------
// out[g*TOK+t][o] = sum_i x[t][i]*mw[g][o][i] + bias(g,o)
//
// R4 restructure: 256x256 tile, 512 threads (8 waves, 2M x 4N), BK=64,
// minimum 2-phase schedule (catalog T3 recipe / m230):
//   iter k: issue A[k+1]->regs + B[k+1]->Bs[nxt] FIRST (full-MFMA-section
//   flight), then ds_read frags + MFMA on [cur], then cvt+ds_write A[k+1]
//   (compiler waits vmcnt(4): A done, B still in flight), then ONE
//   __syncthreads() per K-step.
// Rationale (R3 post-mortem): 128^2 @ 4 waves is structurally latency-bound
// (per-wave 64x64 = 32 MFMA/K-step can't cover pipeline latency; measured
// 327 TF, all pipes <25%). 256^2 doubles per-wave math (64 MFMA/K-step),
// halves A re-reads (2 ntiles not 4), halves barriers per FLOP.
// LDS tiles bf16 [row][64 u16], XOR-swizzled: 16B chunk p = c ^ (row&7)
// (2-way bank aliasing only = free). Same verified involution as R0-R3.
// LDS = 2*32K (A) + 2*32K (B) = 128 KB -> 1 block/CU, 8 waves = 2/SIMD.
__global__ __launch_bounds__(512, 2) void gemm_kernel(
    const float* __restrict__ x, const u16* __restrict__ mw,
    const float* __restrict__ coeff, const float* __restrict__ be,
    const float* __restrict__ bsh, float* __restrict__ out)
{
    __shared__ __align__(16) u16 As[2][BM * BK];  // 2 x 32 KB swizzled
    __shared__ __align__(16) u16 Bs[2][BN * BK];  // 2 x 32 KB swizzled

    int bid = blockIdx.x;                // 512 blocks
    // XCD swizzle: bid%8 = XCD. Each XCD owns 4 whole groups (16 blocks/grp);
    // consecutive i pairs are ntile-siblings sharing an A panel (L2 hit).
    int xcd = bid & 7;
    int i   = bid >> 3;                  // 0..63 within XCD
    int g = xcd * 4 + (i >> 4);
    int t = i & 15;
    int mtile = t >> 1;                  // 0..7
    int ntile = t & 1;                   // 0..1

    const float* Ag = x + ((size_t)g * TOK + (size_t)mtile * BM) * IN_F;
    const u16*   Bg = mw + (size_t)g * OUT_F * IN_F + (size_t)ntile * BN * IN_F;

    int tid  = threadIdx.x;
    int lane = tid & 63;
    int wave = tid >> 6;                 // 0..7
    int wm = wave >> 2;                  // 0..1 (M halves of 128)
    int wn = wave & 3;                   // 0..3 (N quarters of 64)
    int lm = lane & 15, lq = lane >> 4;

    f32x4 acc[8][4];                     // mi 0..7 (128 rows), ni 0..3 (64 cols)
#pragma unroll
    for (int mi = 0; mi < 8; ++mi)
#pragma unroll
        for (int ni = 0; ni < 4; ++ni)
            acc[mi][ni] = f32x4{0.f, 0.f, 0.f, 0.f};

    // ---- prologue: stage tile 0 into buffer 0 ----
    f32x4 areg[8];
    // A tile 0: thread covers 16B fp32 chunk L = j*512+tid; row=L>>4,
    // col4=(L&15)*4 (16 chunks x 64 floats per row). Coalesced.
#pragma unroll
    for (int j = 0; j < 8; ++j) {
        int L = j * 512 + tid;
        areg[j] = *(const f32x4*)(Ag + (size_t)(L >> 4) * IN_F + (L & 15) * 4);
    }
    // B tile 0: async global->LDS; dest linear in chunk index (HW constraint),
    // source chunk XOR-permuted within the 128B row segment (coalesced).
#pragma unroll
    for (int q = 0; q < 4; ++q) {
        int cidx = q * 512 + tid;        // 16B chunk 0..2047
        int r = cidx >> 3;               // row 0..255
        int c = (cidx & 7) ^ (r & 7);    // src chunk (involution)
        __builtin_amdgcn_global_load_lds(
            (const __attribute__((address_space(1))) void*)(Bg + (size_t)r * IN_F + c * 8),
            (__attribute__((address_space(3))) void*)(&Bs[0][(size_t)cidx * 8]),
            16, 0, 0);
    }
    // cvt A0 (compiler waits the 8 A loads; B stays in flight until barrier)
#pragma unroll
    for (int j = 0; j < 8; ++j) {
        int L = j * 512 + tid;
        int r = L >> 4, c4 = L & 15;
        int p = (c4 >> 1) ^ (r & 7);
        bf16x4 bv;
        bv[0] = (__bf16)areg[j][0];
        bv[1] = (__bf16)areg[j][1];
        bv[2] = (__bf16)areg[j][2];
        bv[3] = (__bf16)areg[j][3];
        *(bf16x4*)(&As[0][r * 64 + p * 8 + (c4 & 1) * 4]) = bv;
    }
    __syncthreads();  // tile 0 ready

    // ---- main loop: one barrier per K-tile ----
#pragma unroll
    for (int kk = 0; kk < NKT; ++kk) {
        const int cur = kk & 1;
        const int nxt = cur ^ 1;
        const bool more = (kk + 1 < NKT);

        // (1) issue next tile FIRST: A[k+1] -> regs, B[k+1] -> Bs[nxt].
        //     Flight spans the whole MFMA section below.
        if (more) {
            int k1 = (kk + 1) * BK;
#pragma unroll
            for (int j = 0; j < 8; ++j) {
                int L = j * 512 + tid;
                areg[j] = *(const f32x4*)(Ag + (size_t)(L >> 4) * IN_F + k1 + (L & 15) * 4);
            }
#pragma unroll
            for (int q = 0; q < 4; ++q) {
                int cidx = q * 512 + tid;
                int r = cidx >> 3;
                int c = (cidx & 7) ^ (r & 7);
                __builtin_amdgcn_global_load_lds(
                    (const __attribute__((address_space(1))) void*)(Bg + (size_t)r * IN_F + k1 + c * 8),
                    (__attribute__((address_space(3))) void*)(&Bs[nxt][(size_t)cidx * 8]),
                    16, 0, 0);
            }
        }

        // (2) compute on buffer [cur]: per ks, read frags then 32 MFMA.
#pragma unroll
        for (int ks = 0; ks < 2; ++ks) {
            bf16x8 af[8], bfv[4];
#pragma unroll
            for (int mi = 0; mi < 8; ++mi) {
                int r = wm * 128 + mi * 16 + lm;
                int p = (ks * 4 + lq) ^ (r & 7);
                af[mi] = *(const bf16x8*)(&As[cur][r * 64 + p * 8]);
            }
#pragma unroll
            for (int ni = 0; ni < 4; ++ni) {
                int r = wn * 64 + ni * 16 + lm;
                int p = (ks * 4 + lq) ^ (r & 7);
                bfv[ni] = *(const bf16x8*)(&Bs[cur][r * 64 + p * 8]);
            }
#pragma unroll
            for (int mi = 0; mi < 8; ++mi)
#pragma unroll
                for (int ni = 0; ni < 4; ++ni)
                    acc[mi][ni] = __builtin_amdgcn_mfma_f32_16x16x32_bf16(
                        af[mi], bfv[ni], acc[mi][ni], 0, 0, 0);
        }

        // (3) cvt + swizzled ds_write A[k+1] into As[nxt]. Compiler inserts
        //     counted vmcnt(4) for areg (A done; B[k+1] stays in flight).
        if (more) {
#pragma unroll
            for (int j = 0; j < 8; ++j) {
                int L = j * 512 + tid;
                int r = L >> 4, c4 = L & 15;
                int p = (c4 >> 1) ^ (r & 7);
                bf16x4 bv;
                bv[0] = (__bf16)areg[j][0];
                bv[1] = (__bf16)areg[j][1];
                bv[2] = (__bf16)areg[j][2];
                bv[3] = (__bf16)areg[j][3];
                *(bf16x4*)(&As[nxt][r * 64 + p * 8 + (c4 & 1) * 4]) = bv;
            }
            // (4) single barrier per K-step: drains B[k+1] (had the whole
            //     MFMA section + cvt in flight) + A ds_writes.
            __syncthreads();
        }
    }

    // epilogue: C/D layout col=lane&15, row=(lane>>4)*4+reg  [m89/m91]
    int c0 = ntile * BN + wn * 64;
    float cg[NEXP];
#pragma unroll
    for (int e = 0; e < NEXP; ++e) cg[e] = coeff[g * NEXP + e];
    float bias[4];
#pragma unroll
    for (int ni = 0; ni < 4; ++ni) {
        int o = c0 + ni * 16 + lm;
        float v = bsh[o];
#pragma unroll
        for (int e = 0; e < NEXP; ++e) v += cg[e] * be[e * OUT_F + o];
        bias[ni] = v;
    }

    size_t rowbase = (size_t)g * TOK + (size_t)mtile * BM + (size_t)wm * 128;
#pragma unroll
    for (int mi = 0; mi < 8; ++mi) {
#pragma unroll
        for (int rr = 0; rr < 4; ++rr) {
            size_t row = rowbase + mi * 16 + lq * 4 + rr;
            float* orow = out + row * OUT_F;
#pragma unroll
            for (int ni = 0; ni < 4; ++ni)
                orow[c0 + ni * 16 + lm] = acc[mi][ni][rr] + bias[ni];
        }
    }
}

extern "C" void kernel_launch(void* const* d_in, const int* in_sizes, int n_in,
                              void* d_out, int out_size, void* d_ws, size_t ws_size,
                              hipStream_t stream) {
    const float* x     = (const float*)d_in[0];  // [65536][512] fp32
    const float* coeff = (const float*)d_in[1];  // [32][8]
    const float* We    = (const float*)d_in[2];  // [8][512][512]
    const float* be    = (const float*)d_in[3];  // [8][512]
    const float* Wsh   = (const float*)d_in[4];  // [512][512]
    const float* bsh   = (const float*)d_in[5];  // [512]
    float* out = (float*)d_out;

    u16* mw = (u16*)d_ws;  // bf16 [32][512][512] = exactly 16 MiB

    mix_w_kernel<<<dim3(OUT_F * IN_F / (256 * 4), 4), 256, 0, stream>>>(coeff, We, Wsh, mw);

    int grid = NGROUPS * (TOK / BM) * (OUT_F / BN);  // 32*8*2 = 512
    gemm_kernel<<<grid, 512, 0, stream>>>(x, mw, coeff, be, bsh, out);
}